// Round 1
// baseline (882.143 us; speedup 1.0000x reference)
//
#include <hip/hip_runtime.h>

#define NROWS   131072
#define INDIM   512
#define HIDD    128
#define KCB     256

// ---- d_ws layout (32-bit word offsets) ----
#define OFF_A     0u        // 3*128*256 = 98304 : folded codebook matrices
#define OFF_CV    98304u    // 3*256            : folded bias terms
#define OFF_LOG   99072u    // 131072           : logits
#define OFF_HIST  230144u   // 65536            : top-16-bit histogram
#define OFF_META  295680u   // 16               : cntA, cntB, p, Sp
#define OFF_LISTA 295696u   // 64*2
#define OFF_LISTB 295824u   // 2048*2
#define LISTB_CAP 2048u

__device__ __forceinline__ unsigned order_key(float f) {
    unsigned u = __float_as_uint(f);
    return u ^ ((u & 0x80000000u) ? 0xFFFFFFFFu : 0x80000000u);
}

// ---------------------------------------------------------------------------
// Precompute A_c[j][k] = (1/||cb_k||) * sum_d W_c[j][d]*cb_k[d]
//            cv_c[k]   = (1/||cb_k||) * sum_d  b_c[d]*cb_k[d]
// grid = 24 blocks (3 codebooks x 8 j-groups), 256 threads (one per k)
// ---------------------------------------------------------------------------
__global__ __launch_bounds__(256) void vq_precompute(
    const float* __restrict__ Wm, const float* __restrict__ bm,
    const float* __restrict__ Wt, const float* __restrict__ bt,
    const float* __restrict__ Wp, const float* __restrict__ bp,
    const float* __restrict__ cbm, const float* __restrict__ cbt, const float* __restrict__ cbp,
    float* __restrict__ A, float* __restrict__ cv)
{
    const int c  = blockIdx.x >> 3;
    const int jg = (blockIdx.x & 7) * 16;
    const float* W  = (c == 0) ? Wm  : (c == 1) ? Wt  : Wp;
    const float* bb = (c == 0) ? bm  : (c == 1) ? bt  : bp;
    const float* cb = (c == 0) ? cbm : (c == 1) ? cbt : cbp;
    const int k = threadIdx.x;
    const float4* cbr = (const float4*)(cb + (size_t)k * HIDD);
    float s = 0.f;
    for (int d = 0; d < HIDD / 4; ++d) {
        float4 x = cbr[d];
        s += x.x * x.x + x.y * x.y + x.z * x.z + x.w * x.w;
    }
    const float rn = 1.f / fmaxf(sqrtf(s), 1e-12f);
    for (int j = jg; j < jg + 16; ++j) {
        const float4* wr = (const float4*)(W + (size_t)j * HIDD);
        float acc = 0.f;
        for (int d = 0; d < HIDD / 4; ++d) {
            float4 x = cbr[d]; float4 w = wr[d];
            acc += x.x * w.x + x.y * w.y + x.z * w.z + x.w * w.w;
        }
        A[((size_t)c * HIDD + j) * KCB + k] = acc * rn;
    }
    if (jg == 0) {
        const float4* br = (const float4*)bb;
        float acc = 0.f;
        for (int d = 0; d < HIDD / 4; ++d) {
            float4 x = cbr[d]; float4 w = br[d];
            acc += x.x * w.x + x.y * w.y + x.z * w.z + x.w * w.w;
        }
        cv[(size_t)c * KCB + k] = acc * rn;
    }
}

// ---------------------------------------------------------------------------
// Main fused kernel: 64 rows per block, 256 threads.
// LDS: T = 32 KiB k-major tile (a1^T, later H^T), S = 16 KiB staging. 48 KiB
// total -> 3 blocks/CU. Thread grid: ty = t>>4 (4 rows), tx = t&15.
// ---------------------------------------------------------------------------
__global__ __launch_bounds__(256, 3) void vq_main(
    const float* __restrict__ h0, const float* __restrict__ W1, const float* __restrict__ b1,
    const float* __restrict__ W2, const float* __restrict__ b2,
    const float* __restrict__ A, const float* __restrict__ cv, const float* __restrict__ wsv,
    int* __restrict__ codes, float* __restrict__ logits, unsigned* __restrict__ hist)
{
    __shared__ float T[HIDD * 64];   // 32 KiB, [k][row]
    __shared__ float S[4096];        // 16 KiB staging

    const int t  = threadIdx.x;
    const int tx = t & 15;
    const int ty = t >> 4;
    const int row0 = blockIdx.x * 64;

    // ---------------- phase 1: a1 = relu(h0 @ W1 + b1) -> T (transposed)
    {
        float acc[4][8] = {};
        for (int kc = 0; kc < INDIM; kc += 16) {
            {
                const int rr = t >> 2, kq = (t & 3) * 4;
                float4 v = *(const float4*)(h0 + (size_t)(row0 + rr) * INDIM + kc + kq);
                S[(kq + 0) * 64 + rr] = v.x;
                S[(kq + 1) * 64 + rr] = v.y;
                S[(kq + 2) * 64 + rr] = v.z;
                S[(kq + 3) * 64 + rr] = v.w;
                const float4* src = (const float4*)(W1 + (size_t)kc * HIDD);
                float4* dst = (float4*)(S + 1024);
                dst[t]       = src[t];
                dst[t + 256] = src[t + 256];
            }
            __syncthreads();
            #pragma unroll 8
            for (int k = 0; k < 16; ++k) {
                float4 av  = *(const float4*)&S[k * 64 + 4 * ty];
                float4 b0  = *(const float4*)&S[1024 + k * HIDD + 4 * tx];
                float4 b1v = *(const float4*)&S[1024 + k * HIDD + 64 + 4 * tx];
                float aa[4] = {av.x, av.y, av.z, av.w};
                float bbv[8] = {b0.x, b0.y, b0.z, b0.w, b1v.x, b1v.y, b1v.z, b1v.w};
                #pragma unroll
                for (int r = 0; r < 4; ++r)
                    #pragma unroll
                    for (int j = 0; j < 8; ++j)
                        acc[r][j] = fmaf(aa[r], bbv[j], acc[r][j]);
            }
            __syncthreads();
        }
        float4 bv0 = *(const float4*)&b1[4 * tx];
        float4 bv1 = *(const float4*)&b1[4 * tx + 64];
        float ba[8] = {bv0.x, bv0.y, bv0.z, bv0.w, bv1.x, bv1.y, bv1.z, bv1.w};
        #pragma unroll
        for (int i = 0; i < 2; ++i)
            #pragma unroll
            for (int j = 0; j < 4; ++j) {
                const int c = 4 * tx + 64 * i + j;
                float4 col;
                col.x = fmaxf(acc[0][i * 4 + j] + ba[i * 4 + j], 0.f);
                col.y = fmaxf(acc[1][i * 4 + j] + ba[i * 4 + j], 0.f);
                col.z = fmaxf(acc[2][i * 4 + j] + ba[i * 4 + j], 0.f);
                col.w = fmaxf(acc[3][i * 4 + j] + ba[i * 4 + j], 0.f);
                *(float4*)&T[c * 64 + 4 * ty] = col;
            }
    }
    __syncthreads();

    // ---------------- phase 2: H = relu(a1 @ W2 + b2) in regs, overwrite T with H^T
    {
        float acc[4][8] = {};
        for (int kc = 0; kc < HIDD; kc += 16) {
            const float4* src = (const float4*)(W2 + (size_t)kc * HIDD);
            float4* dst = (float4*)S;
            dst[t]       = src[t];
            dst[t + 256] = src[t + 256];
            __syncthreads();
            #pragma unroll 8
            for (int k = 0; k < 16; ++k) {
                float4 av  = *(const float4*)&T[(kc + k) * 64 + 4 * ty];
                float4 b0  = *(const float4*)&S[k * HIDD + 4 * tx];
                float4 b1v = *(const float4*)&S[k * HIDD + 64 + 4 * tx];
                float aa[4] = {av.x, av.y, av.z, av.w};
                float bbv[8] = {b0.x, b0.y, b0.z, b0.w, b1v.x, b1v.y, b1v.z, b1v.w};
                #pragma unroll
                for (int r = 0; r < 4; ++r)
                    #pragma unroll
                    for (int j = 0; j < 8; ++j)
                        acc[r][j] = fmaf(aa[r], bbv[j], acc[r][j]);
            }
            __syncthreads();   // also guarantees all reads of T are done
        }
        float4 bv0 = *(const float4*)&b2[4 * tx];
        float4 bv1 = *(const float4*)&b2[4 * tx + 64];
        float ba[8] = {bv0.x, bv0.y, bv0.z, bv0.w, bv1.x, bv1.y, bv1.z, bv1.w};
        #pragma unroll
        for (int i = 0; i < 2; ++i)
            #pragma unroll
            for (int j = 0; j < 4; ++j) {
                const int c = 4 * tx + 64 * i + j;
                float4 col;
                col.x = fmaxf(acc[0][i * 4 + j] + ba[i * 4 + j], 0.f);
                col.y = fmaxf(acc[1][i * 4 + j] + ba[i * 4 + j], 0.f);
                col.z = fmaxf(acc[2][i * 4 + j] + ba[i * 4 + j], 0.f);
                col.w = fmaxf(acc[3][i * 4 + j] + ba[i * 4 + j], 0.f);
                *(float4*)&T[c * 64 + 4 * ty] = col;
            }
    }
    __syncthreads();

    // ---------------- phase 3: per codebook, sims = H @ A_c (+ cv_c), row argmin
    for (int cbk = 0; cbk < 3; ++cbk) {
        float acc[4][16] = {};
        for (int kc = 0; kc < HIDD; kc += 16) {
            const float4* src = (const float4*)(A + ((size_t)(cbk * HIDD + kc)) * KCB);
            float4* dst = (float4*)S;
            #pragma unroll
            for (int i = 0; i < 4; ++i) dst[t + 256 * i] = src[t + 256 * i];
            __syncthreads();
            #pragma unroll 4
            for (int k = 0; k < 16; ++k) {
                float4 av = *(const float4*)&T[(kc + k) * 64 + 4 * ty];
                float aa[4] = {av.x, av.y, av.z, av.w};
                #pragma unroll
                for (int i = 0; i < 4; ++i) {
                    float4 bv = *(const float4*)&S[k * KCB + 4 * tx + 64 * i];
                    float bbv[4] = {bv.x, bv.y, bv.z, bv.w};
                    #pragma unroll
                    for (int r = 0; r < 4; ++r)
                        #pragma unroll
                        for (int j = 0; j < 4; ++j)
                            acc[r][i * 4 + j] = fmaf(aa[r], bbv[j], acc[r][i * 4 + j]);
                }
            }
            __syncthreads();
        }
        float mv[4] = {3.4e38f, 3.4e38f, 3.4e38f, 3.4e38f};
        int   mi[4] = {0, 0, 0, 0};
        #pragma unroll
        for (int i = 0; i < 4; ++i) {
            float4 cvv = *(const float4*)&cv[cbk * KCB + 4 * tx + 64 * i];
            float ca[4] = {cvv.x, cvv.y, cvv.z, cvv.w};
            #pragma unroll
            for (int j = 0; j < 4; ++j) {
                const int c = 64 * i + 4 * tx + j;   // ascending within thread
                #pragma unroll
                for (int r = 0; r < 4; ++r) {
                    float v = acc[r][i * 4 + j] + ca[j];
                    if (v < mv[r]) { mv[r] = v; mi[r] = c; }
                }
            }
        }
        // reduce across the 16 lanes sharing these 4 rows (same wave)
        #pragma unroll
        for (int d = 1; d < 16; d <<= 1) {
            #pragma unroll
            for (int r = 0; r < 4; ++r) {
                float ov = __shfl_xor(mv[r], d);
                int   oi = __shfl_xor(mi[r], d);
                if (ov < mv[r] || (ov == mv[r] && oi < mi[r])) { mv[r] = ov; mi[r] = oi; }
            }
        }
        if (tx == 0) {
            #pragma unroll
            for (int r = 0; r < 4; ++r)
                codes[(size_t)(row0 + 4 * ty + r) * 3 + cbk] = mi[r];
        }
    }

    // ---------------- phase 4: logits + global histogram of order keys
    if (t < HIDD) S[t] = wsv[t];
    __syncthreads();
    if (t < 64) {
        float s = 0.f;
        #pragma unroll 8
        for (int k = 0; k < HIDD; ++k) s = fmaf(T[k * 64 + t], S[k], s);
        logits[row0 + t] = s;
        atomicAdd(&hist[order_key(s) >> 16], 1u);
    }
}

// ---------------------------------------------------------------------------
// Find cutoff bin p: (# elements in bins > p) < 32 <= (# in bins >= p)
// ---------------------------------------------------------------------------
__global__ __launch_bounds__(1024) void vq_findp(const unsigned* __restrict__ hist,
                                                 unsigned* __restrict__ meta)
{
    __shared__ unsigned Tb[1024];
    __shared__ unsigned sIg, sPg;
    const int t = threadIdx.x;
    unsigned s = 0;
    const uint4* hv = (const uint4*)(hist + (size_t)t * 64);
    for (int j = 0; j < 16; ++j) { uint4 h = hv[j]; s += h.x + h.y + h.z + h.w; }
    Tb[t] = s;
    __syncthreads();
    for (int d = 1; d < 1024; d <<= 1) {           // inclusive suffix sum
        unsigned v = (t + d < 1024) ? Tb[t + d] : 0u;
        __syncthreads();
        Tb[t] += v;
        __syncthreads();
    }
    const unsigned Ti = Tb[t];
    const unsigned P  = Ti - s;
    if (P < 32u && Ti >= 32u) { sIg = (unsigned)t; sPg = P; }
    __syncthreads();
    const int ig = (int)sIg;
    const unsigned Pg = sPg;
    if (t < 64) {
        unsigned c = hist[ig * 64 + t];
        unsigned Tw = c;
        #pragma unroll
        for (int d = 1; d < 64; d <<= 1) {
            unsigned v = __shfl_down(Tw, d);
            if (t + d < 64) Tw += v;
        }
        unsigned Pl = Pg + Tw - c;
        if (Pl < 32u && Pl + c >= 32u) { meta[2] = (unsigned)(ig * 64 + t); meta[3] = Pl; }
    }
}

// ---------------------------------------------------------------------------
// Collect candidates: bin > p -> list A (all selected), bin == p -> list B
// ---------------------------------------------------------------------------
__global__ __launch_bounds__(256) void vq_collect(
    const float* __restrict__ logits, unsigned* __restrict__ meta,
    unsigned* __restrict__ listA, unsigned* __restrict__ listB)
{
    const int i = blockIdx.x * 256 + threadIdx.x;
    const unsigned key = order_key(logits[i]);
    const unsigned p = meta[2];
    const unsigned b = key >> 16;
    if (b > p) {
        unsigned idx = atomicAdd(&meta[0], 1u);
        if (idx < 64u) { listA[2 * idx] = key; listA[2 * idx + 1] = (unsigned)i; }
    } else if (b == p) {
        unsigned idx = atomicAdd(&meta[1], 1u);
        if (idx < LISTB_CAP) { listB[2 * idx] = key; listB[2 * idx + 1] = (unsigned)i; }
    }
}

// ---------------------------------------------------------------------------
// Ordered selection of 32 (value desc, index asc — jax.lax.top_k semantics)
// ---------------------------------------------------------------------------
__global__ void vq_final(const unsigned* __restrict__ meta,
                         const unsigned* __restrict__ listA, const unsigned* __restrict__ listB,
                         const int* __restrict__ codes,
                         int* __restrict__ outki, int* __restrict__ outsel)
{
    if (threadIdx.x != 0 || blockIdx.x != 0) return;
    unsigned nAv = meta[0]; int nA = (nAv > 64u) ? 64 : (int)nAv;
    unsigned nBv = meta[1]; int nB = (nBv > LISTB_CAP) ? (int)LISTB_CAP : (int)nBv;
    unsigned lk = 0u, li = 0u;
    bool first = true;
    for (int m = 0; m < 32; ++m) {
        int best = -1; unsigned bk = 0u, bi = 0u;
        for (int j = 0; j < nA + nB; ++j) {
            unsigned k2, ix;
            if (j < nA) { k2 = listA[2 * j]; ix = listA[2 * j + 1]; }
            else        { int jj = j - nA; k2 = listB[2 * jj]; ix = listB[2 * jj + 1]; }
            if (!first) {
                bool after = (k2 < lk) || (k2 == lk && ix > li);
                if (!after) continue;
            }
            if (best < 0 || k2 > bk || (k2 == bk && ix < bi)) { best = j; bk = k2; bi = ix; }
        }
        if (best < 0) { bk = lk; bi = 0u; }  // defensive; cannot trigger with N >= 32
        outki[m] = (int)bi;
        lk = bk; li = bi; first = false;
    }
    for (int m = 0; m < 32; ++m) {
        const int idx = outki[m];
        outsel[3 * m + 0] = codes[3 * idx + 0];
        outsel[3 * m + 1] = codes[3 * idx + 1];
        outsel[3 * m + 2] = codes[3 * idx + 2];
    }
}

// ---------------------------------------------------------------------------
extern "C" void kernel_launch(void* const* d_in, const int* in_sizes, int n_in,
                              void* d_out, int out_size, void* d_ws, size_t ws_size,
                              hipStream_t stream)
{
    (void)in_sizes; (void)n_in; (void)out_size; (void)ws_size;

    const float* h0  = (const float*)d_in[0];
    const float* W1  = (const float*)d_in[1];
    const float* b1  = (const float*)d_in[2];
    const float* W2  = (const float*)d_in[3];
    const float* b2  = (const float*)d_in[4];
    const float* Wm  = (const float*)d_in[5];
    const float* bm  = (const float*)d_in[6];
    const float* Wt  = (const float*)d_in[7];
    const float* bt  = (const float*)d_in[8];
    const float* Wp  = (const float*)d_in[9];
    const float* bp  = (const float*)d_in[10];
    const float* cbm = (const float*)d_in[11];
    const float* cbt = (const float*)d_in[12];
    const float* cbp = (const float*)d_in[13];
    const float* wsv = (const float*)d_in[14];

    float*    wsf   = (float*)d_ws;
    unsigned* wsu   = (unsigned*)d_ws;
    float*    A     = wsf + OFF_A;
    float*    cvv   = wsf + OFF_CV;
    float*    logit = wsf + OFF_LOG;
    unsigned* hist  = wsu + OFF_HIST;
    unsigned* meta  = wsu + OFF_META;
    unsigned* listA = wsu + OFF_LISTA;
    unsigned* listB = wsu + OFF_LISTB;

    int* codes  = (int*)d_out;
    int* outki  = codes + (size_t)NROWS * 3;
    int* outsel = outki + 32;

    hipMemsetAsync((void*)hist, 0, (65536 + 16) * sizeof(unsigned), stream);
    vq_precompute<<<24, 256, 0, stream>>>(Wm, bm, Wt, bt, Wp, bp, cbm, cbt, cbp, A, cvv);
    vq_main<<<NROWS / 64, 256, 0, stream>>>(h0, W1, b1, W2, b2, A, cvv, wsv, codes, logit, hist);
    vq_findp<<<1, 1024, 0, stream>>>(hist, meta);
    vq_collect<<<NROWS / 256, 256, 0, stream>>>(logit, meta, listA, listB);
    vq_final<<<1, 64, 0, stream>>>(meta, listA, listB, codes, outki, outsel);
}

// Round 2
// 714.585 us; speedup vs baseline: 1.2345x; 1.2345x over previous
//
#include <hip/hip_runtime.h>

#define NROWS   131072
#define INDIM   512
#define HIDD    128
#define KCB     256
#define RPB     128   // rows per block

// ---- d_ws layout (32-bit word offsets) ----
#define OFF_A     0u        // 3*128*256 = 98304 : folded codebook matrices
#define OFF_CV    98304u    // 3*256            : folded bias terms
#define OFF_LOG   99072u    // 131072           : logits
#define OFF_HIST  230144u   // 65536            : top-16-bit histogram
#define OFF_META  295680u   // 16               : cntA, cntB, p, Sp
#define OFF_LISTA 295696u   // 64*2
#define OFF_LISTB 295824u   // 2048*2
#define LISTB_CAP 2048u

__device__ __forceinline__ unsigned order_key(float f) {
    unsigned u = __float_as_uint(f);
    return u ^ ((u & 0x80000000u) ? 0xFFFFFFFFu : 0x80000000u);
}

// ---------------------------------------------------------------------------
// Precompute A_c[j][k] = (1/||cb_k||) * sum_d W_c[j][d]*cb_k[d]
//            cv_c[k]   = (1/||cb_k||) * sum_d  b_c[d]*cb_k[d]
// Also zeros hist+meta (stream-ordered before vq_main).
// grid = 24 blocks (3 codebooks x 8 j-groups), 256 threads (one per k)
// ---------------------------------------------------------------------------
__global__ __launch_bounds__(256) void vq_precompute(
    const float* __restrict__ Wm, const float* __restrict__ bm,
    const float* __restrict__ Wt, const float* __restrict__ bt,
    const float* __restrict__ Wp, const float* __restrict__ bp,
    const float* __restrict__ cbm, const float* __restrict__ cbt, const float* __restrict__ cbp,
    float* __restrict__ A, float* __restrict__ cv, unsigned* __restrict__ hist)
{
    // zero hist (65536) + meta (16), contiguous
    for (unsigned i = blockIdx.x * 256u + threadIdx.x; i < 65536u + 16u; i += 24u * 256u)
        hist[i] = 0u;

    const int c  = blockIdx.x >> 3;
    const int jg = (blockIdx.x & 7) * 16;
    const float* W  = (c == 0) ? Wm  : (c == 1) ? Wt  : Wp;
    const float* bb = (c == 0) ? bm  : (c == 1) ? bt  : bp;
    const float* cb = (c == 0) ? cbm : (c == 1) ? cbt : cbp;
    const int k = threadIdx.x;
    const float4* cbr = (const float4*)(cb + (size_t)k * HIDD);
    float s = 0.f;
    for (int d = 0; d < HIDD / 4; ++d) {
        float4 x = cbr[d];
        s += x.x * x.x + x.y * x.y + x.z * x.z + x.w * x.w;
    }
    const float rn = 1.f / fmaxf(sqrtf(s), 1e-12f);
    for (int j = jg; j < jg + 16; ++j) {
        const float4* wr = (const float4*)(W + (size_t)j * HIDD);
        float acc = 0.f;
        for (int d = 0; d < HIDD / 4; ++d) {
            float4 x = cbr[d]; float4 w = wr[d];
            acc += x.x * w.x + x.y * w.y + x.z * w.z + x.w * w.w;
        }
        A[((size_t)c * HIDD + j) * KCB + k] = acc * rn;
    }
    if (jg == 0) {
        const float4* br = (const float4*)bb;
        float acc = 0.f;
        for (int d = 0; d < HIDD / 4; ++d) {
            float4 x = cbr[d]; float4 w = br[d];
            acc += x.x * w.x + x.y * w.y + x.z * w.z + x.w * w.w;
        }
        cv[(size_t)c * KCB + k] = acc * rn;
    }
}

// ---------------------------------------------------------------------------
// Main fused kernel: 128 rows per block, 256 threads (tx 0..15, ty 0..15).
// LDS: T = 64 KiB [k][row] tile (a1^T, later H^T), S = 16 KiB staging.
// 80 KiB total -> 2 blocks/CU. Thread tile: 8 rows x 8 cols (ph1/2),
// 8 rows x 16 cols (ph3).
// ---------------------------------------------------------------------------
__global__ __launch_bounds__(256, 2) void vq_main(
    const float* __restrict__ h0, const float* __restrict__ W1, const float* __restrict__ bias1,
    const float* __restrict__ W2, const float* __restrict__ bias2,
    const float* __restrict__ Amat, const float* __restrict__ cv, const float* __restrict__ wsv,
    int* __restrict__ codes, float* __restrict__ logits, unsigned* __restrict__ hist)
{
    __shared__ float T[HIDD * RPB];  // 64 KiB, [k][row]
    __shared__ float S[4096];        // 16 KiB staging

    const int t  = threadIdx.x;
    const int tx = t & 15;
    const int ty = t >> 4;
    const int row0 = blockIdx.x * RPB;

    // ---------------- phase 1: a1 = relu(h0 @ W1 + b1) -> T (transposed)
    {
        float acc[8][8] = {};
        const int srow = t >> 1;
        const int sq   = (t & 1) * 8;
        const float* hp = h0 + (size_t)(row0 + srow) * INDIM + sq;
        for (int kc = 0; kc < INDIM; kc += 16) {
            float4 ha = *(const float4*)(hp + kc);
            float4 hb = *(const float4*)(hp + kc + 4);
            const float4* wsrc = (const float4*)(W1 + (size_t)kc * HIDD);
            float4 w0 = wsrc[t];
            float4 w1 = wsrc[t + 256];
            __syncthreads();                       // prev chunk's S reads done
            // h0^T chunk -> S[0..2047], bank-friendly (2 lanes/bank)
            S[(sq + 0) * RPB + srow] = ha.x;
            S[(sq + 1) * RPB + srow] = ha.y;
            S[(sq + 2) * RPB + srow] = ha.z;
            S[(sq + 3) * RPB + srow] = ha.w;
            S[(sq + 4) * RPB + srow] = hb.x;
            S[(sq + 5) * RPB + srow] = hb.y;
            S[(sq + 6) * RPB + srow] = hb.z;
            S[(sq + 7) * RPB + srow] = hb.w;
            // W1 chunk -> S[2048..4095]
            float4* wdst = (float4*)(S + 2048);
            wdst[t]       = w0;
            wdst[t + 256] = w1;
            __syncthreads();                       // S ready
            #pragma unroll
            for (int k = 0; k < 16; ++k) {
                float4 a0 = *(const float4*)&S[k * RPB + 8 * ty];
                float4 a1 = *(const float4*)&S[k * RPB + 8 * ty + 4];
                float4 b0 = *(const float4*)&S[2048 + k * HIDD + 4 * tx];
                float4 b1v = *(const float4*)&S[2048 + k * HIDD + 4 * tx + 64];
                float aa[8] = {a0.x, a0.y, a0.z, a0.w, a1.x, a1.y, a1.z, a1.w};
                float bb[8] = {b0.x, b0.y, b0.z, b0.w, b1v.x, b1v.y, b1v.z, b1v.w};
                #pragma unroll
                for (int r = 0; r < 8; ++r)
                    #pragma unroll
                    for (int j = 0; j < 8; ++j)
                        acc[r][j] = fmaf(aa[r], bb[j], acc[r][j]);
            }
        }
        float4 bv0 = *(const float4*)&bias1[4 * tx];
        float4 bv1 = *(const float4*)&bias1[4 * tx + 64];
        float ba[8] = {bv0.x, bv0.y, bv0.z, bv0.w, bv1.x, bv1.y, bv1.z, bv1.w};
        // no barrier needed: T untouched by anyone yet
        #pragma unroll
        for (int i = 0; i < 2; ++i)
            #pragma unroll
            for (int j = 0; j < 4; ++j) {
                const int c = 4 * tx + 64 * i + j;
                float4 lo, hi;
                lo.x = fmaxf(acc[0][i * 4 + j] + ba[i * 4 + j], 0.f);
                lo.y = fmaxf(acc[1][i * 4 + j] + ba[i * 4 + j], 0.f);
                lo.z = fmaxf(acc[2][i * 4 + j] + ba[i * 4 + j], 0.f);
                lo.w = fmaxf(acc[3][i * 4 + j] + ba[i * 4 + j], 0.f);
                hi.x = fmaxf(acc[4][i * 4 + j] + ba[i * 4 + j], 0.f);
                hi.y = fmaxf(acc[5][i * 4 + j] + ba[i * 4 + j], 0.f);
                hi.z = fmaxf(acc[6][i * 4 + j] + ba[i * 4 + j], 0.f);
                hi.w = fmaxf(acc[7][i * 4 + j] + ba[i * 4 + j], 0.f);
                *(float4*)&T[c * RPB + 8 * ty]     = lo;
                *(float4*)&T[c * RPB + 8 * ty + 4] = hi;
            }
    }

    // ---------------- phase 2: H = relu(a1 @ W2 + b2), overwrite T with H^T
    {
        float acc[8][8] = {};
        for (int kc = 0; kc < HIDD; kc += 16) {
            const float4* wsrc = (const float4*)(W2 + (size_t)kc * HIDD);
            float4 w0 = wsrc[t];
            float4 w1 = wsrc[t + 256];
            __syncthreads();                       // prev S reads + (kc==0) T writes ordered
            float4* wdst = (float4*)S;
            wdst[t]       = w0;
            wdst[t + 256] = w1;
            __syncthreads();
            #pragma unroll
            for (int k = 0; k < 16; ++k) {
                float4 a0 = *(const float4*)&T[(kc + k) * RPB + 8 * ty];
                float4 a1 = *(const float4*)&T[(kc + k) * RPB + 8 * ty + 4];
                float4 b0 = *(const float4*)&S[k * HIDD + 4 * tx];
                float4 b1v = *(const float4*)&S[k * HIDD + 4 * tx + 64];
                float aa[8] = {a0.x, a0.y, a0.z, a0.w, a1.x, a1.y, a1.z, a1.w};
                float bb[8] = {b0.x, b0.y, b0.z, b0.w, b1v.x, b1v.y, b1v.z, b1v.w};
                #pragma unroll
                for (int r = 0; r < 8; ++r)
                    #pragma unroll
                    for (int j = 0; j < 8; ++j)
                        acc[r][j] = fmaf(aa[r], bb[j], acc[r][j]);
            }
        }
        __syncthreads();                            // all T reads done before overwrite
        float4 bv0 = *(const float4*)&bias2[4 * tx];
        float4 bv1 = *(const float4*)&bias2[4 * tx + 64];
        float ba[8] = {bv0.x, bv0.y, bv0.z, bv0.w, bv1.x, bv1.y, bv1.z, bv1.w};
        #pragma unroll
        for (int i = 0; i < 2; ++i)
            #pragma unroll
            for (int j = 0; j < 4; ++j) {
                const int c = 4 * tx + 64 * i + j;
                float4 lo, hi;
                lo.x = fmaxf(acc[0][i * 4 + j] + ba[i * 4 + j], 0.f);
                lo.y = fmaxf(acc[1][i * 4 + j] + ba[i * 4 + j], 0.f);
                lo.z = fmaxf(acc[2][i * 4 + j] + ba[i * 4 + j], 0.f);
                lo.w = fmaxf(acc[3][i * 4 + j] + ba[i * 4 + j], 0.f);
                hi.x = fmaxf(acc[4][i * 4 + j] + ba[i * 4 + j], 0.f);
                hi.y = fmaxf(acc[5][i * 4 + j] + ba[i * 4 + j], 0.f);
                hi.z = fmaxf(acc[6][i * 4 + j] + ba[i * 4 + j], 0.f);
                hi.w = fmaxf(acc[7][i * 4 + j] + ba[i * 4 + j], 0.f);
                *(float4*)&T[c * RPB + 8 * ty]     = lo;
                *(float4*)&T[c * RPB + 8 * ty + 4] = hi;
            }
    }

    // ---------------- phase 3: per codebook, sims = H @ A_c (+ cv_c), row argmin
    for (int cbk = 0; cbk < 3; ++cbk) {
        float acc[8][16] = {};
        for (int kc = 0; kc < HIDD; kc += 16) {
            const float4* src = (const float4*)(Amat + ((size_t)cbk * HIDD + kc) * KCB);
            float4 s0 = src[t];
            float4 s1 = src[t + 256];
            float4 s2 = src[t + 512];
            float4 s3 = src[t + 768];
            __syncthreads();                       // prev S reads (and T writes) ordered
            float4* dst = (float4*)S;
            dst[t]       = s0;
            dst[t + 256] = s1;
            dst[t + 512] = s2;
            dst[t + 768] = s3;
            __syncthreads();
            #pragma unroll
            for (int k = 0; k < 16; ++k) {
                float4 a0 = *(const float4*)&T[(kc + k) * RPB + 8 * ty];
                float4 a1 = *(const float4*)&T[(kc + k) * RPB + 8 * ty + 4];
                float aa[8] = {a0.x, a0.y, a0.z, a0.w, a1.x, a1.y, a1.z, a1.w};
                #pragma unroll
                for (int i = 0; i < 4; ++i) {
                    float4 bv = *(const float4*)&S[k * KCB + 4 * tx + 64 * i];
                    float bb[4] = {bv.x, bv.y, bv.z, bv.w};
                    #pragma unroll
                    for (int r = 0; r < 8; ++r)
                        #pragma unroll
                        for (int j = 0; j < 4; ++j)
                            acc[r][i * 4 + j] = fmaf(aa[r], bb[j], acc[r][i * 4 + j]);
                }
            }
        }
        float mv[8] = {3.4e38f, 3.4e38f, 3.4e38f, 3.4e38f, 3.4e38f, 3.4e38f, 3.4e38f, 3.4e38f};
        int   mi[8] = {0, 0, 0, 0, 0, 0, 0, 0};
        #pragma unroll
        for (int i = 0; i < 4; ++i) {
            float4 cvv = *(const float4*)&cv[cbk * KCB + 4 * tx + 64 * i];
            float ca[4] = {cvv.x, cvv.y, cvv.z, cvv.w};
            #pragma unroll
            for (int j = 0; j < 4; ++j) {
                const int c = 64 * i + 4 * tx + j;   // ascending within thread
                #pragma unroll
                for (int r = 0; r < 8; ++r) {
                    float v = acc[r][i * 4 + j] + ca[j];
                    if (v < mv[r]) { mv[r] = v; mi[r] = c; }
                }
            }
        }
        // reduce across the 16 lanes (tx) sharing these 8 rows (same wave)
        #pragma unroll
        for (int d = 1; d < 16; d <<= 1) {
            #pragma unroll
            for (int r = 0; r < 8; ++r) {
                float ov = __shfl_xor(mv[r], d);
                int   oi = __shfl_xor(mi[r], d);
                if (ov < mv[r] || (ov == mv[r] && oi < mi[r])) { mv[r] = ov; mi[r] = oi; }
            }
        }
        if (tx == 0) {
            #pragma unroll
            for (int r = 0; r < 8; ++r)
                codes[(size_t)(row0 + 8 * ty + r) * 3 + cbk] = mi[r];
        }
    }

    // ---------------- phase 4: logits + global histogram of order keys
    __syncthreads();                                // last cb's S reads done
    if (t < HIDD) S[t] = wsv[t];
    __syncthreads();
    if (t < RPB) {
        float s = 0.f;
        #pragma unroll 8
        for (int k = 0; k < HIDD; ++k) s = fmaf(T[k * RPB + t], S[k], s);
        logits[row0 + t] = s;
        atomicAdd(&hist[order_key(s) >> 16], 1u);
    }
}

// ---------------------------------------------------------------------------
// Find cutoff bin p: (# elements in bins > p) < 32 <= (# in bins >= p)
// ---------------------------------------------------------------------------
__global__ __launch_bounds__(1024) void vq_findp(const unsigned* __restrict__ hist,
                                                 unsigned* __restrict__ meta)
{
    __shared__ unsigned Tb[1024];
    __shared__ unsigned sIg, sPg;
    const int t = threadIdx.x;
    unsigned s = 0;
    const uint4* hv = (const uint4*)(hist + (size_t)t * 64);
    for (int j = 0; j < 16; ++j) { uint4 h = hv[j]; s += h.x + h.y + h.z + h.w; }
    Tb[t] = s;
    __syncthreads();
    for (int d = 1; d < 1024; d <<= 1) {           // inclusive suffix sum
        unsigned v = (t + d < 1024) ? Tb[t + d] : 0u;
        __syncthreads();
        Tb[t] += v;
        __syncthreads();
    }
    const unsigned Ti = Tb[t];
    const unsigned P  = Ti - s;
    if (P < 32u && Ti >= 32u) { sIg = (unsigned)t; sPg = P; }
    __syncthreads();
    const int ig = (int)sIg;
    const unsigned Pg = sPg;
    if (t < 64) {
        unsigned c = hist[ig * 64 + t];
        unsigned Tw = c;
        #pragma unroll
        for (int d = 1; d < 64; d <<= 1) {
            unsigned v = __shfl_down(Tw, d);
            if (t + d < 64) Tw += v;
        }
        unsigned Pl = Pg + Tw - c;
        if (Pl < 32u && Pl + c >= 32u) { meta[2] = (unsigned)(ig * 64 + t); meta[3] = Pl; }
    }
}

// ---------------------------------------------------------------------------
// Collect candidates: bin > p -> list A (all selected), bin == p -> list B
// ---------------------------------------------------------------------------
__global__ __launch_bounds__(256) void vq_collect(
    const float* __restrict__ logits, unsigned* __restrict__ meta,
    unsigned* __restrict__ listA, unsigned* __restrict__ listB)
{
    const int i = blockIdx.x * 256 + threadIdx.x;
    const unsigned key = order_key(logits[i]);
    const unsigned p = meta[2];
    const unsigned b = key >> 16;
    if (b > p) {
        unsigned idx = atomicAdd(&meta[0], 1u);
        if (idx < 64u) { listA[2 * idx] = key; listA[2 * idx + 1] = (unsigned)i; }
    } else if (b == p) {
        unsigned idx = atomicAdd(&meta[1], 1u);
        if (idx < LISTB_CAP) { listB[2 * idx] = key; listB[2 * idx + 1] = (unsigned)i; }
    }
}

// ---------------------------------------------------------------------------
// Parallel ordered selection of 32 (value desc, index asc — lax.top_k semantics)
// rank-by-counting over the candidate union; ranks are unique since (key,idx)
// pairs are distinct.
// ---------------------------------------------------------------------------
__global__ __launch_bounds__(256) void vq_final(
    const unsigned* __restrict__ meta,
    const unsigned* __restrict__ listA, const unsigned* __restrict__ listB,
    const int* __restrict__ codes,
    int* __restrict__ outki, int* __restrict__ outsel)
{
    __shared__ unsigned Ks[64 + LISTB_CAP];
    __shared__ unsigned Is[64 + LISTB_CAP];
    __shared__ int sel[32];
    const int t = threadIdx.x;
    const unsigned nAv = meta[0];
    const unsigned nBv = meta[1];
    const int nA = (nAv > 64u) ? 64 : (int)nAv;
    const int nB = (nBv > LISTB_CAP) ? (int)LISTB_CAP : (int)nBv;
    const int n  = nA + nB;
    for (int j = t; j < n; j += 256) {
        if (j < nA) { Ks[j] = listA[2 * j]; Is[j] = listA[2 * j + 1]; }
        else        { int jj = j - nA; Ks[j] = listB[2 * jj]; Is[j] = listB[2 * jj + 1]; }
    }
    __syncthreads();
    for (int j = t; j < n; j += 256) {
        const unsigned kj = Ks[j], ij = Is[j];
        int rank = 0;
        for (int m = 0; m < n; ++m) {
            const unsigned km = Ks[m], im = Is[m];
            rank += (km > kj) || (km == kj && im < ij);
        }
        if (rank < 32) sel[rank] = (int)ij;
    }
    __syncthreads();
    if (t < 32) outki[t] = sel[t];
    if (t < 96) outsel[t] = codes[3 * sel[t / 3] + (t % 3)];
}

// ---------------------------------------------------------------------------
extern "C" void kernel_launch(void* const* d_in, const int* in_sizes, int n_in,
                              void* d_out, int out_size, void* d_ws, size_t ws_size,
                              hipStream_t stream)
{
    (void)in_sizes; (void)n_in; (void)out_size; (void)ws_size;

    const float* h0  = (const float*)d_in[0];
    const float* W1  = (const float*)d_in[1];
    const float* b1  = (const float*)d_in[2];
    const float* W2  = (const float*)d_in[3];
    const float* b2  = (const float*)d_in[4];
    const float* Wm  = (const float*)d_in[5];
    const float* bm  = (const float*)d_in[6];
    const float* Wt  = (const float*)d_in[7];
    const float* bt  = (const float*)d_in[8];
    const float* Wp  = (const float*)d_in[9];
    const float* bp  = (const float*)d_in[10];
    const float* cbm = (const float*)d_in[11];
    const float* cbt = (const float*)d_in[12];
    const float* cbp = (const float*)d_in[13];
    const float* wsv = (const float*)d_in[14];

    float*    wsf   = (float*)d_ws;
    unsigned* wsu   = (unsigned*)d_ws;
    float*    A     = wsf + OFF_A;
    float*    cvv   = wsf + OFF_CV;
    float*    logit = wsf + OFF_LOG;
    unsigned* hist  = wsu + OFF_HIST;
    unsigned* meta  = wsu + OFF_META;
    unsigned* listA = wsu + OFF_LISTA;
    unsigned* listB = wsu + OFF_LISTB;

    int* codes  = (int*)d_out;
    int* outki  = codes + (size_t)NROWS * 3;
    int* outsel = outki + 32;

    vq_precompute<<<24, 256, 0, stream>>>(Wm, bm, Wt, bt, Wp, bp, cbm, cbt, cbp, A, cvv, hist);
    vq_main<<<NROWS / RPB, 256, 0, stream>>>(h0, W1, b1, W2, b2, A, cvv, wsv, codes, logit, hist);
    vq_findp<<<1, 1024, 0, stream>>>(hist, meta);
    vq_collect<<<NROWS / 256, 256, 0, stream>>>(logit, meta, listA, listB);
    vq_final<<<1, 256, 0, stream>>>(meta, listA, listB, codes, outki, outsel);
}

// Round 3
// 713.305 us; speedup vs baseline: 1.2367x; 1.0018x over previous
//
#include <hip/hip_runtime.h>

#define NROWS   131072
#define INDIM   512
#define HIDD    128
#define KCB     256
#define RPB     128   // rows per block

// ---- d_ws layout (32-bit word offsets) ----
#define OFF_A     0u        // 3*128*256 = 98304 : folded codebook matrices
#define OFF_CV    98304u    // 3*256            : folded bias terms
#define OFF_LOG   99072u    // 131072           : logits
#define OFF_HIST  230144u   // 65536            : top-16-bit histogram
#define OFF_META  295680u   // 16               : cntA, cntB, p, Sp
#define OFF_LISTA 295696u   // 64*2
#define OFF_LISTB 295824u   // 2048*2
#define LISTB_CAP 2048u

__device__ __forceinline__ unsigned order_key(float f) {
    unsigned u = __float_as_uint(f);
    return u ^ ((u & 0x80000000u) ? 0xFFFFFFFFu : 0x80000000u);
}

// ---------------------------------------------------------------------------
// Precompute A_c[j][k] = (1/||cb_k||) * sum_d W_c[j][d]*cb_k[d]
//            cv_c[k]   = (1/||cb_k||) * sum_d  b_c[d]*cb_k[d]
// Also zeros hist+meta (stream-ordered before vq_main).
// grid = 24 blocks (3 codebooks x 8 j-groups), 256 threads (one per k)
// ---------------------------------------------------------------------------
__global__ __launch_bounds__(256) void vq_precompute(
    const float* __restrict__ Wm, const float* __restrict__ bm,
    const float* __restrict__ Wt, const float* __restrict__ bt,
    const float* __restrict__ Wp, const float* __restrict__ bp,
    const float* __restrict__ cbm, const float* __restrict__ cbt, const float* __restrict__ cbp,
    float* __restrict__ A, float* __restrict__ cv, unsigned* __restrict__ hist)
{
    // zero hist (65536) + meta (16), contiguous
    for (unsigned i = blockIdx.x * 256u + threadIdx.x; i < 65536u + 16u; i += 24u * 256u)
        hist[i] = 0u;

    const int c  = blockIdx.x >> 3;
    const int jg = (blockIdx.x & 7) * 16;
    const float* W  = (c == 0) ? Wm  : (c == 1) ? Wt  : Wp;
    const float* bb = (c == 0) ? bm  : (c == 1) ? bt  : bp;
    const float* cb = (c == 0) ? cbm : (c == 1) ? cbt : cbp;
    const int k = threadIdx.x;
    const float4* cbr = (const float4*)(cb + (size_t)k * HIDD);
    float s = 0.f;
    for (int d = 0; d < HIDD / 4; ++d) {
        float4 x = cbr[d];
        s += x.x * x.x + x.y * x.y + x.z * x.z + x.w * x.w;
    }
    const float rn = 1.f / fmaxf(sqrtf(s), 1e-12f);
    for (int j = jg; j < jg + 16; ++j) {
        const float4* wr = (const float4*)(W + (size_t)j * HIDD);
        float acc = 0.f;
        for (int d = 0; d < HIDD / 4; ++d) {
            float4 x = cbr[d]; float4 w = wr[d];
            acc += x.x * w.x + x.y * w.y + x.z * w.z + x.w * w.w;
        }
        A[((size_t)c * HIDD + j) * KCB + k] = acc * rn;
    }
    if (jg == 0) {
        const float4* br = (const float4*)bb;
        float acc = 0.f;
        for (int d = 0; d < HIDD / 4; ++d) {
            float4 x = cbr[d]; float4 w = br[d];
            acc += x.x * w.x + x.y * w.y + x.z * w.z + x.w * w.w;
        }
        cv[(size_t)c * KCB + k] = acc * rn;
    }
}

// ---------------------------------------------------------------------------
// Main fused kernel: 128 rows per block, 256 threads (tx 0..15, ty 0..15).
// LDS: T = 64 KiB [k][row] tile (a1^T, later H^T), S = 16 KiB staging.
// 80 KiB total -> LDS caps CU at 2 blocks (8 waves). amdgpu_waves_per_eu(2,2)
// pins the register allocator to that occupancy: 256-VGPR budget, no spill
// (round-2 showed the allocator clamping to 128 VGPR and spilling ~110 MB).
// Thread tile: 8x8 (ph1/2), 8x16 (ph3).
// ---------------------------------------------------------------------------
__global__ __launch_bounds__(256)
__attribute__((amdgpu_waves_per_eu(2, 2)))
void vq_main(
    const float* __restrict__ h0, const float* __restrict__ W1, const float* __restrict__ bias1,
    const float* __restrict__ W2, const float* __restrict__ bias2,
    const float* __restrict__ Amat, const float* __restrict__ cv, const float* __restrict__ wsv,
    int* __restrict__ codes, float* __restrict__ logits, unsigned* __restrict__ hist)
{
    __shared__ float T[HIDD * RPB];  // 64 KiB, [k][row]
    __shared__ float S[4096];        // 16 KiB staging

    const int t  = threadIdx.x;
    const int tx = t & 15;
    const int ty = t >> 4;
    const int row0 = blockIdx.x * RPB;

    // ---------------- phase 1: a1 = relu(h0 @ W1 + b1) -> T (transposed)
    {
        float acc[8][8] = {};
        const int srow = t >> 1;
        const int sq   = (t & 1) * 8;
        const float* hp = h0 + (size_t)(row0 + srow) * INDIM + sq;
        for (int kc = 0; kc < INDIM; kc += 16) {
            float4 ha = *(const float4*)(hp + kc);
            float4 hb = *(const float4*)(hp + kc + 4);
            const float4* wsrc = (const float4*)(W1 + (size_t)kc * HIDD);
            float4 w0 = wsrc[t];
            float4 w1 = wsrc[t + 256];
            __syncthreads();                       // prev chunk's S reads done
            // h0^T chunk -> S[0..2047], bank-friendly (2 lanes/bank)
            S[(sq + 0) * RPB + srow] = ha.x;
            S[(sq + 1) * RPB + srow] = ha.y;
            S[(sq + 2) * RPB + srow] = ha.z;
            S[(sq + 3) * RPB + srow] = ha.w;
            S[(sq + 4) * RPB + srow] = hb.x;
            S[(sq + 5) * RPB + srow] = hb.y;
            S[(sq + 6) * RPB + srow] = hb.z;
            S[(sq + 7) * RPB + srow] = hb.w;
            // W1 chunk -> S[2048..4095]
            float4* wdst = (float4*)(S + 2048);
            wdst[t]       = w0;
            wdst[t + 256] = w1;
            __syncthreads();                       // S ready
            #pragma unroll
            for (int k = 0; k < 16; ++k) {
                float4 a0 = *(const float4*)&S[k * RPB + 8 * ty];
                float4 a1 = *(const float4*)&S[k * RPB + 8 * ty + 4];
                float4 b0 = *(const float4*)&S[2048 + k * HIDD + 4 * tx];
                float4 b1v = *(const float4*)&S[2048 + k * HIDD + 4 * tx + 64];
                float aa[8] = {a0.x, a0.y, a0.z, a0.w, a1.x, a1.y, a1.z, a1.w};
                float bb[8] = {b0.x, b0.y, b0.z, b0.w, b1v.x, b1v.y, b1v.z, b1v.w};
                #pragma unroll
                for (int r = 0; r < 8; ++r)
                    #pragma unroll
                    for (int j = 0; j < 8; ++j)
                        acc[r][j] = fmaf(aa[r], bb[j], acc[r][j]);
            }
        }
        float4 bv0 = *(const float4*)&bias1[4 * tx];
        float4 bv1 = *(const float4*)&bias1[4 * tx + 64];
        float ba[8] = {bv0.x, bv0.y, bv0.z, bv0.w, bv1.x, bv1.y, bv1.z, bv1.w};
        // no barrier needed: T untouched by anyone yet
        #pragma unroll
        for (int i = 0; i < 2; ++i)
            #pragma unroll
            for (int j = 0; j < 4; ++j) {
                const int c = 4 * tx + 64 * i + j;
                float4 lo, hi;
                lo.x = fmaxf(acc[0][i * 4 + j] + ba[i * 4 + j], 0.f);
                lo.y = fmaxf(acc[1][i * 4 + j] + ba[i * 4 + j], 0.f);
                lo.z = fmaxf(acc[2][i * 4 + j] + ba[i * 4 + j], 0.f);
                lo.w = fmaxf(acc[3][i * 4 + j] + ba[i * 4 + j], 0.f);
                hi.x = fmaxf(acc[4][i * 4 + j] + ba[i * 4 + j], 0.f);
                hi.y = fmaxf(acc[5][i * 4 + j] + ba[i * 4 + j], 0.f);
                hi.z = fmaxf(acc[6][i * 4 + j] + ba[i * 4 + j], 0.f);
                hi.w = fmaxf(acc[7][i * 4 + j] + ba[i * 4 + j], 0.f);
                *(float4*)&T[c * RPB + 8 * ty]     = lo;
                *(float4*)&T[c * RPB + 8 * ty + 4] = hi;
            }
    }

    // ---------------- phase 2: H = relu(a1 @ W2 + b2), overwrite T with H^T
    {
        float acc[8][8] = {};
        for (int kc = 0; kc < HIDD; kc += 16) {
            const float4* wsrc = (const float4*)(W2 + (size_t)kc * HIDD);
            float4 w0 = wsrc[t];
            float4 w1 = wsrc[t + 256];
            __syncthreads();                       // prev S reads + (kc==0) T writes ordered
            float4* wdst = (float4*)S;
            wdst[t]       = w0;
            wdst[t + 256] = w1;
            __syncthreads();
            #pragma unroll
            for (int k = 0; k < 16; ++k) {
                float4 a0 = *(const float4*)&T[(kc + k) * RPB + 8 * ty];
                float4 a1 = *(const float4*)&T[(kc + k) * RPB + 8 * ty + 4];
                float4 b0 = *(const float4*)&S[k * HIDD + 4 * tx];
                float4 b1v = *(const float4*)&S[k * HIDD + 4 * tx + 64];
                float aa[8] = {a0.x, a0.y, a0.z, a0.w, a1.x, a1.y, a1.z, a1.w};
                float bb[8] = {b0.x, b0.y, b0.z, b0.w, b1v.x, b1v.y, b1v.z, b1v.w};
                #pragma unroll
                for (int r = 0; r < 8; ++r)
                    #pragma unroll
                    for (int j = 0; j < 8; ++j)
                        acc[r][j] = fmaf(aa[r], bb[j], acc[r][j]);
            }
        }
        __syncthreads();                            // all T reads done before overwrite
        float4 bv0 = *(const float4*)&bias2[4 * tx];
        float4 bv1 = *(const float4*)&bias2[4 * tx + 64];
        float ba[8] = {bv0.x, bv0.y, bv0.z, bv0.w, bv1.x, bv1.y, bv1.z, bv1.w};
        #pragma unroll
        for (int i = 0; i < 2; ++i)
            #pragma unroll
            for (int j = 0; j < 4; ++j) {
                const int c = 4 * tx + 64 * i + j;
                float4 lo, hi;
                lo.x = fmaxf(acc[0][i * 4 + j] + ba[i * 4 + j], 0.f);
                lo.y = fmaxf(acc[1][i * 4 + j] + ba[i * 4 + j], 0.f);
                lo.z = fmaxf(acc[2][i * 4 + j] + ba[i * 4 + j], 0.f);
                lo.w = fmaxf(acc[3][i * 4 + j] + ba[i * 4 + j], 0.f);
                hi.x = fmaxf(acc[4][i * 4 + j] + ba[i * 4 + j], 0.f);
                hi.y = fmaxf(acc[5][i * 4 + j] + ba[i * 4 + j], 0.f);
                hi.z = fmaxf(acc[6][i * 4 + j] + ba[i * 4 + j], 0.f);
                hi.w = fmaxf(acc[7][i * 4 + j] + ba[i * 4 + j], 0.f);
                *(float4*)&T[c * RPB + 8 * ty]     = lo;
                *(float4*)&T[c * RPB + 8 * ty + 4] = hi;
            }
    }

    // ---------------- phase 3: per codebook, sims = H @ A_c (+ cv_c), row argmin
    for (int cbk = 0; cbk < 3; ++cbk) {
        float acc[8][16] = {};
        for (int kc = 0; kc < HIDD; kc += 16) {
            const float4* src = (const float4*)(Amat + ((size_t)cbk * HIDD + kc) * KCB);
            float4 s0 = src[t];
            float4 s1 = src[t + 256];
            float4 s2 = src[t + 512];
            float4 s3 = src[t + 768];
            __syncthreads();                       // prev S reads (and T writes) ordered
            float4* dst = (float4*)S;
            dst[t]       = s0;
            dst[t + 256] = s1;
            dst[t + 512] = s2;
            dst[t + 768] = s3;
            __syncthreads();
            #pragma unroll
            for (int k = 0; k < 16; ++k) {
                float4 a0 = *(const float4*)&T[(kc + k) * RPB + 8 * ty];
                float4 a1 = *(const float4*)&T[(kc + k) * RPB + 8 * ty + 4];
                float aa[8] = {a0.x, a0.y, a0.z, a0.w, a1.x, a1.y, a1.z, a1.w};
                #pragma unroll
                for (int i = 0; i < 4; ++i) {
                    float4 bv = *(const float4*)&S[k * KCB + 4 * tx + 64 * i];
                    float bb[4] = {bv.x, bv.y, bv.z, bv.w};
                    #pragma unroll
                    for (int r = 0; r < 8; ++r)
                        #pragma unroll
                        for (int j = 0; j < 4; ++j)
                            acc[r][i * 4 + j] = fmaf(aa[r], bb[j], acc[r][i * 4 + j]);
                }
            }
        }
        float mv[8] = {3.4e38f, 3.4e38f, 3.4e38f, 3.4e38f, 3.4e38f, 3.4e38f, 3.4e38f, 3.4e38f};
        int   mi[8] = {0, 0, 0, 0, 0, 0, 0, 0};
        #pragma unroll
        for (int i = 0; i < 4; ++i) {
            float4 cvv = *(const float4*)&cv[cbk * KCB + 4 * tx + 64 * i];
            float ca[4] = {cvv.x, cvv.y, cvv.z, cvv.w};
            #pragma unroll
            for (int j = 0; j < 4; ++j) {
                const int c = 64 * i + 4 * tx + j;   // ascending within thread
                #pragma unroll
                for (int r = 0; r < 8; ++r) {
                    float v = acc[r][i * 4 + j] + ca[j];
                    if (v < mv[r]) { mv[r] = v; mi[r] = c; }
                }
            }
        }
        // reduce across the 16 lanes (tx) sharing these 8 rows (same wave)
        #pragma unroll
        for (int d = 1; d < 16; d <<= 1) {
            #pragma unroll
            for (int r = 0; r < 8; ++r) {
                float ov = __shfl_xor(mv[r], d);
                int   oi = __shfl_xor(mi[r], d);
                if (ov < mv[r] || (ov == mv[r] && oi < mi[r])) { mv[r] = ov; mi[r] = oi; }
            }
        }
        if (tx == 0) {
            #pragma unroll
            for (int r = 0; r < 8; ++r)
                codes[(size_t)(row0 + 8 * ty + r) * 3 + cbk] = mi[r];
        }
    }

    // ---------------- phase 4: logits + global histogram of order keys
    __syncthreads();                                // last cb's S reads done
    if (t < HIDD) S[t] = wsv[t];
    __syncthreads();
    if (t < RPB) {
        float s = 0.f;
        #pragma unroll 8
        for (int k = 0; k < HIDD; ++k) s = fmaf(T[k * RPB + t], S[k], s);
        logits[row0 + t] = s;
        atomicAdd(&hist[order_key(s) >> 16], 1u);
    }
}

// ---------------------------------------------------------------------------
// Find cutoff bin p: (# elements in bins > p) < 32 <= (# in bins >= p)
// ---------------------------------------------------------------------------
__global__ __launch_bounds__(1024) void vq_findp(const unsigned* __restrict__ hist,
                                                 unsigned* __restrict__ meta)
{
    __shared__ unsigned Tb[1024];
    __shared__ unsigned sIg, sPg;
    const int t = threadIdx.x;
    unsigned s = 0;
    const uint4* hv = (const uint4*)(hist + (size_t)t * 64);
    for (int j = 0; j < 16; ++j) { uint4 h = hv[j]; s += h.x + h.y + h.z + h.w; }
    Tb[t] = s;
    __syncthreads();
    for (int d = 1; d < 1024; d <<= 1) {           // inclusive suffix sum
        unsigned v = (t + d < 1024) ? Tb[t + d] : 0u;
        __syncthreads();
        Tb[t] += v;
        __syncthreads();
    }
    const unsigned Ti = Tb[t];
    const unsigned P  = Ti - s;
    if (P < 32u && Ti >= 32u) { sIg = (unsigned)t; sPg = P; }
    __syncthreads();
    const int ig = (int)sIg;
    const unsigned Pg = sPg;
    if (t < 64) {
        unsigned c = hist[ig * 64 + t];
        unsigned Tw = c;
        #pragma unroll
        for (int d = 1; d < 64; d <<= 1) {
            unsigned v = __shfl_down(Tw, d);
            if (t + d < 64) Tw += v;
        }
        unsigned Pl = Pg + Tw - c;
        if (Pl < 32u && Pl + c >= 32u) { meta[2] = (unsigned)(ig * 64 + t); meta[3] = Pl; }
    }
}

// ---------------------------------------------------------------------------
// Collect candidates: bin > p -> list A (all selected), bin == p -> list B
// ---------------------------------------------------------------------------
__global__ __launch_bounds__(256) void vq_collect(
    const float* __restrict__ logits, unsigned* __restrict__ meta,
    unsigned* __restrict__ listA, unsigned* __restrict__ listB)
{
    const int i = blockIdx.x * 256 + threadIdx.x;
    const unsigned key = order_key(logits[i]);
    const unsigned p = meta[2];
    const unsigned b = key >> 16;
    if (b > p) {
        unsigned idx = atomicAdd(&meta[0], 1u);
        if (idx < 64u) { listA[2 * idx] = key; listA[2 * idx + 1] = (unsigned)i; }
    } else if (b == p) {
        unsigned idx = atomicAdd(&meta[1], 1u);
        if (idx < LISTB_CAP) { listB[2 * idx] = key; listB[2 * idx + 1] = (unsigned)i; }
    }
}

// ---------------------------------------------------------------------------
// Parallel ordered selection of 32 (value desc, index asc — lax.top_k semantics)
// rank-by-counting over the candidate union; ranks are unique since (key,idx)
// pairs are distinct.
// ---------------------------------------------------------------------------
__global__ __launch_bounds__(256) void vq_final(
    const unsigned* __restrict__ meta,
    const unsigned* __restrict__ listA, const unsigned* __restrict__ listB,
    const int* __restrict__ codes,
    int* __restrict__ outki, int* __restrict__ outsel)
{
    __shared__ unsigned Ks[64 + LISTB_CAP];
    __shared__ unsigned Is[64 + LISTB_CAP];
    __shared__ int sel[32];
    const int t = threadIdx.x;
    const unsigned nAv = meta[0];
    const unsigned nBv = meta[1];
    const int nA = (nAv > 64u) ? 64 : (int)nAv;
    const int nB = (nBv > LISTB_CAP) ? (int)LISTB_CAP : (int)nBv;
    const int n  = nA + nB;
    for (int j = t; j < n; j += 256) {
        if (j < nA) { Ks[j] = listA[2 * j]; Is[j] = listA[2 * j + 1]; }
        else        { int jj = j - nA; Ks[j] = listB[2 * jj]; Is[j] = listB[2 * jj + 1]; }
    }
    __syncthreads();
    for (int j = t; j < n; j += 256) {
        const unsigned kj = Ks[j], ij = Is[j];
        int rank = 0;
        for (int m = 0; m < n; ++m) {
            const unsigned km = Ks[m], im = Is[m];
            rank += (km > kj) || (km == kj && im < ij);
        }
        if (rank < 32) sel[rank] = (int)ij;
    }
    __syncthreads();
    if (t < 32) outki[t] = sel[t];
    if (t < 96) outsel[t] = codes[3 * sel[t / 3] + (t % 3)];
}

// ---------------------------------------------------------------------------
extern "C" void kernel_launch(void* const* d_in, const int* in_sizes, int n_in,
                              void* d_out, int out_size, void* d_ws, size_t ws_size,
                              hipStream_t stream)
{
    (void)in_sizes; (void)n_in; (void)out_size; (void)ws_size;

    const float* h0  = (const float*)d_in[0];
    const float* W1  = (const float*)d_in[1];
    const float* b1  = (const float*)d_in[2];
    const float* W2  = (const float*)d_in[3];
    const float* b2  = (const float*)d_in[4];
    const float* Wm  = (const float*)d_in[5];
    const float* bm  = (const float*)d_in[6];
    const float* Wt  = (const float*)d_in[7];
    const float* bt  = (const float*)d_in[8];
    const float* Wp  = (const float*)d_in[9];
    const float* bp  = (const float*)d_in[10];
    const float* cbm = (const float*)d_in[11];
    const float* cbt = (const float*)d_in[12];
    const float* cbp = (const float*)d_in[13];
    const float* wsv = (const float*)d_in[14];

    float*    wsf   = (float*)d_ws;
    unsigned* wsu   = (unsigned*)d_ws;
    float*    A     = wsf + OFF_A;
    float*    cvv   = wsf + OFF_CV;
    float*    logit = wsf + OFF_LOG;
    unsigned* hist  = wsu + OFF_HIST;
    unsigned* meta  = wsu + OFF_META;
    unsigned* listA = wsu + OFF_LISTA;
    unsigned* listB = wsu + OFF_LISTB;

    int* codes  = (int*)d_out;
    int* outki  = codes + (size_t)NROWS * 3;
    int* outsel = outki + 32;

    vq_precompute<<<24, 256, 0, stream>>>(Wm, bm, Wt, bt, Wp, bp, cbm, cbt, cbp, A, cvv, hist);
    vq_main<<<NROWS / RPB, 256, 0, stream>>>(h0, W1, b1, W2, b2, A, cvv, wsv, codes, logit, hist);
    vq_findp<<<1, 1024, 0, stream>>>(hist, meta);
    vq_collect<<<NROWS / 256, 256, 0, stream>>>(logit, meta, listA, listB);
    vq_final<<<1, 256, 0, stream>>>(meta, listA, listB, codes, outki, outsel);
}